// Round 2
// baseline (143.342 us; speedup 1.0000x reference)
//
#include <hip/hip_runtime.h>
#include <math.h>

#define A_ 5
#define C_ 20
#define N_ 64
#define H_ 52
#define W_ 52
#define HW_ (H_ * W_)        // 2704
#define M_ 32
#define CH_ (A_ * (5 + C_))  // 125
#define CPB 64               // cells per block
#define NBLK_X ((HW_ + CPB - 1) / CPB)  // 43
#define NBLK (NBLK_X * N_)              // 2752

// Block = 320 threads = 5 waves; wave a computes anchor a for 64 cells.
// Each anchor-wave computes its own CE + bbox terms with fully-coalesced
// score loads (x read exactly once); tail is LDS-only select.
__global__ __launch_bounds__(320) void yolo_main(
    const float* __restrict__ x,       // (N, 125, H, W)
    const float* __restrict__ anchors, // (5, 2)
    const float* __restrict__ gt,      // (N, 32, 4)
    const int* __restrict__ glab,      // (N, 32)
    const void* img_h_p, const void* img_w_p,
    float* __restrict__ ws)            // SoA: (3, NBLK)
{
    // SoA exchange: [component][anchor][cell] — stride-1 in cell, conflict-free
    __shared__ float s_c[5][A_][CPB];  // bi, bu, ov, ce, bb

    const int tid  = threadIdx.x;
    const int a    = tid >> 6;    // anchor 0..4 (wave id)
    const int lane = tid & 63;    // cell within block chunk
    const int n    = blockIdx.y;
    const int cell = blockIdx.x * CPB + lane;
    const bool valid = cell < HW_;

    // img scale (int per spec; float-bit-pattern fallback)
    int ibw = *(const int*)img_w_p;
    float img_w = (ibw > 0 && ibw < 1000000) ? (float)ibw : *(const float*)img_w_p;
    int ibh = *(const int*)img_h_p;
    float img_h = (ibh > 0 && ibh < 1000000) ? (float)ibh : *(const float*)img_h_p;
    const float sx = img_w / (float)W_;   // 32
    const float sy = img_h / (float)H_;   // 32

    const float ax = anchors[2 * a];       // wave-uniform
    const float ay = anchors[2 * a + 1];

    float bi = 0.f, bu = 1.f;   // best inter/union (cross-mult argmax)
    int   bm = 0;
    float ov = 0.f, ce = 0.f, bb = 0.f;

    if (valid) {
        const int wi = cell % W_;
        const int hi = cell / W_;
        const size_t base = (size_t)n * CH_ * HW_ + (size_t)a * 25 * HW_ + cell;
        float t0 = x[base];
        float t1 = x[base + (size_t)HW_];
        float t2 = x[base + 2 * (size_t)HW_];
        float t3 = x[base + 3 * (size_t)HW_];
        float t4 = x[base + 4 * (size_t)HW_];
        // issue this wave's OWN 20 score-channel loads now (coalesced 256B each);
        // they complete under the IoU loop's VALU work
        float sc[C_];
        #pragma unroll
        for (int j = 0; j < C_; ++j)
            sc[j] = x[base + (size_t)(5 + j) * HW_];

        float bx = 1.f / (1.f + __expf(-t0)) + (float)wi * sx;
        float by = 1.f / (1.f + __expf(-t1)) + (float)hi * sy;
        float bw = sx * ax * __expf(t2);
        float bh = sy * ay * __expf(t3);
        float x1 = bx, y1 = by, x2 = bx + bw, y2 = by + bh;
        ov = 1.f / (1.f + __expf(-t4));
        // match reference exactly: area from corner differences
        float ap = (x2 - x1) * (y2 - y1);

        const float4* gtv = (const float4*)(gt + (size_t)n * M_ * 4);
        #pragma unroll 8
        for (int m = 0; m < M_; ++m) {
            float4 g = gtv[m];                 // uniform address -> scalar load
            float area = (g.z - g.x) * (g.w - g.y);
            float wxi = fminf(x2, g.z) - fmaxf(x1, g.x);
            float hyi = fminf(y2, g.w) - fmaxf(y1, g.y);
            wxi = fmaxf(wxi, 0.f);
            hyi = fmaxf(hyi, 0.f);
            float inter = wxi * hyi;
            float uni = ap + area - inter;
            if (inter * bu > bi * uni) { bi = inter; bu = uni; bm = m; }
        }

        // per-anchor bbox term (only used if this anchor wins and bi>0)
        float4 g = ((const float4*)gt)[n * M_ + bm];  // divergent, L1-resident 512B
        int lab = glab[n * M_ + bm];                  // divergent, L1-resident 128B
        float d0 = x1 - g.x;
        float d1 = y1 - g.y;
        float d2 = sqrtf(x2) - sqrtf(g.z);
        float d3 = sqrtf(y2) - sqrtf(g.w);
        bb = d0 * d0 + d1 * d1 + d2 * d2 + d3 * d3;

        // per-anchor CE: exact two-pass log-softmax over registers
        float mx = sc[0];
        #pragma unroll
        for (int j = 1; j < C_; ++j) mx = fmaxf(mx, sc[j]);
        float se = 0.f, scl = sc[0];
        #pragma unroll
        for (int j = 0; j < C_; ++j) {
            se += __expf(sc[j] - mx);
            scl = (j == lab) ? sc[j] : scl;   // compile-time index, stays in regs
        }
        ce = mx + __logf(se) - scl;
    }

    s_c[0][a][lane] = bi;
    s_c[1][a][lane] = bu;
    s_c[2][a][lane] = ov;
    s_c[3][a][lane] = ce;
    s_c[4][a][lane] = bb;
    __syncthreads();

    // ---- tail: wave 0 selects best anchor per cell — LDS+VALU only ----
    if (tid < 64) {
        float Bi = 0.f, Bu = 1.f, O = 0.f, CE = 0.f, BB = 0.f;
        float bomax = -1e30f;
        #pragma unroll
        for (int aa = 0; aa < A_; ++aa) {
            float ci = s_c[0][aa][lane];
            float cu = s_c[1][aa][lane];
            float co = s_c[2][aa][lane];
            bomax = fmaxf(bomax, co);
            bool upd = (aa == 0) || (ci * Bu > Bi * cu);
            if (upd) {
                Bi = ci; Bu = cu; O = co;
                CE = s_c[3][aa][lane];
                BB = s_c[4][aa][lane];
            }
        }

        float obj = 0.f, bbx = 0.f, clf = 0.f;
        if (valid) {
            if (Bi > 0.f) {
                float d = O - Bi / Bu;
                obj = d * d;
                bbx = BB;
                clf = CE;
            } else {
                obj = 0.5f * bomax * bomax;
            }
        }

        #pragma unroll
        for (int off = 32; off > 0; off >>= 1) {
            obj += __shfl_down(obj, off, 64);
            bbx += __shfl_down(bbx, off, 64);
            clf += __shfl_down(clf, off, 64);
        }
        if (tid == 0) {
            const int bid = blockIdx.y * gridDim.x + blockIdx.x;
            ws[0 * NBLK + bid] = obj;   // SoA so reduce reads coalesce
            ws[1 * NBLK + bid] = bbx;
            ws[2 * NBLK + bid] = clf;
        }
    }
}

__global__ __launch_bounds__(1024) void yolo_reduce(
    const float* __restrict__ ws, float* __restrict__ out)
{
    __shared__ float s_red[16][3];
    const int tid = threadIdx.x;
    float o = 0.f, b = 0.f, c = 0.f;
    for (int e = tid; e < NBLK; e += 1024) {   // 3 coalesced iterations
        o += ws[0 * NBLK + e];
        b += ws[1 * NBLK + e];
        c += ws[2 * NBLK + e];
    }
    #pragma unroll
    for (int off = 32; off > 0; off >>= 1) {
        o += __shfl_down(o, off, 64);
        b += __shfl_down(b, off, 64);
        c += __shfl_down(c, off, 64);
    }
    const int wid = tid >> 6;
    if ((tid & 63) == 0) {
        s_red[wid][0] = o; s_red[wid][1] = b; s_red[wid][2] = c;
    }
    __syncthreads();
    if (tid == 0) {
        float oo = 0.f, bb = 0.f, cc = 0.f;
        #pragma unroll
        for (int w = 0; w < 16; ++w) {
            oo += s_red[w][0]; bb += s_red[w][1]; cc += s_red[w][2];
        }
        out[0] = oo; out[1] = bb; out[2] = cc;
    }
}

extern "C" void kernel_launch(void* const* d_in, const int* in_sizes, int n_in,
                              void* d_out, int out_size, void* d_ws, size_t ws_size,
                              hipStream_t stream) {
    (void)in_sizes; (void)n_in; (void)out_size; (void)ws_size;
    const float* x    = (const float*)d_in[0];
    const float* anch = (const float*)d_in[1];
    const float* gt   = (const float*)d_in[2];
    const int*   gl   = (const int*)d_in[3];
    const void*  ih   = d_in[4];
    const void*  iw   = d_in[5];
    float* out = (float*)d_out;
    float* ws  = (float*)d_ws;

    dim3 grid(NBLK_X, N_);
    yolo_main<<<grid, dim3(320), 0, stream>>>(x, anch, gt, gl, ih, iw, ws);
    yolo_reduce<<<1, 1024, 0, stream>>>(ws, out);
}